// Round 4
// baseline (397.583 us; speedup 1.0000x reference)
//
#include <hip/hip_runtime.h>
#include <stdint.h>
#include <math.h>

// Problem constants (B,T,J,D) = (64, 2048, 128, 512)
#define BB 64
#define TT 2048
#define JJ 128
#define DD 512
#define BK 32    // K chunk per step (one 16x16x32 MFMA K)

typedef short short8 __attribute__((ext_vector_type(8)));
typedef float f32x4 __attribute__((ext_vector_type(4)));

__device__ inline unsigned pk_hi(float a, float b) {
  // (hi16(a)) | (hi16(b) << 16) -- bf16 truncation pack of 2 fp32
  return __builtin_amdgcn_perm(__float_as_uint(b), __float_as_uint(a), 0x07060302u);
}
__device__ inline float truncbf(float x) {
  return __uint_as_float(__float_as_uint(x) & 0xFFFF0000u);
}
// 8 fp32 (two float4) -> hi chunk (8 bf16) + lo chunk (8 bf16)
__device__ inline void pack8(float4 a, float4 b, uint4& h, uint4& l) {
  h = make_uint4(pk_hi(a.x, a.y), pk_hi(a.z, a.w), pk_hi(b.x, b.y), pk_hi(b.z, b.w));
  float l0 = a.x - truncbf(a.x), l1 = a.y - truncbf(a.y);
  float l2 = a.z - truncbf(a.z), l3 = a.w - truncbf(a.w);
  float l4 = b.x - truncbf(b.x), l5 = b.y - truncbf(b.y);
  float l6 = b.z - truncbf(b.z), l7 = b.w - truncbf(b.w);
  l = make_uint4(pk_hi(l0, l1), pk_hi(l2, l3), pk_hi(l4, l5), pk_hi(l6, l7));
}
__device__ inline short8 bc8(uint4 u) { return __builtin_bit_cast(short8, u); }

// ---------------- Kernel A0: pre-pack Q*w into hi/lo bf16 FRAGMENT images ----
// Layout: [b][ks (16)][stripe (2)][mi (4)][lane (64)] uint4.
// Entry (b,ks,str,mi,lane) = bf16x8 fragment for MFMA A-operand:
//   row j = str*64 + mi*16 + (lane&15), k-slice chunk c = lane>>4 (8 floats).
// A GEMM wave then loads its 4 A-fragments as contiguous, fully-coalesced
// 1 KB-per-instruction global loads (no LDS round-trip needed).
__global__ __launch_bounds__(256)
void qpack_kernel(const float* __restrict__ Qm, const float* __restrict__ w,
                  uint4* __restrict__ Qhi, uint4* __restrict__ Qlo) {
  const int gid = blockIdx.x * 256 + threadIdx.x;  // 0 .. 524287
  const int lane = gid & 63;
  const int mi = (gid >> 6) & 3;
  const int str = (gid >> 8) & 1;
  const int ks = (gid >> 9) & 15;
  const int b = gid >> 13;
  const int j = str * 64 + mi * 16 + (lane & 15);
  const int c = lane >> 4;

  const float* qp = Qm + ((size_t)b * JJ + j) * DD + ks * BK + c * 8;
  const float* wp = w + ks * BK + c * 8;
  float4 a = *(const float4*)qp;
  float4 bq = *(const float4*)(qp + 4);
  float4 wa = *(const float4*)wp;
  float4 wb = *(const float4*)(wp + 4);
  a.x *= wa.x; a.y *= wa.y; a.z *= wa.z; a.w *= wa.w;
  bq.x *= wb.x; bq.y *= wb.y; bq.z *= wb.z; bq.w *= wb.w;
  uint4 h, l;
  pack8(a, bq, h, l);
  Qhi[gid] = h;
  Qlo[gid] = l;
}

// ---------------- Kernel A: S[b][j][t] = sum_d (Q[b][j][d]*w[d]) * C[b][t][d]
// 128x128 tile, split-bf16 (hi/lo) 3-MFMA scheme, 16 K-steps of 32.
// LDS-FREE: A fragments load directly from the pre-packed fragment image
// (contiguous per-wave); B fragments are lane-local 32 B slices of context
// rows, converted fp32->hi/lo bf16 in-register. No barriers anywhere ->
// the compiler pipelines next-step loads under current-step MFMAs, waves
// are fully independent, and dead-j waves retire immediately.
// Dead-work elimination (bit-exact): blocks with t0 >= clen[b] retire
// (their S is never read); j-row-tiles >= qlen[b] skipped (never read).
__global__ __launch_bounds__(256, 1)
void sim_gemm_mfma(const uint4* __restrict__ Qhi, const uint4* __restrict__ Qlo,
                   const float* __restrict__ Cm, const int* __restrict__ qlen,
                   const int* __restrict__ clen, float* __restrict__ S) {
  // XCD-aware swizzle: 1024 blocks, 8 XCDs -> XCD x gets b in [x*8, x*8+8)
  // so each XCD's L2 only needs 8 b's of Qpk (4 MB) for the 16x A-reuse.
  const int id = blockIdx.x;
  const int nid = (id & 7) * 128 + (id >> 3);
  const int b = nid >> 4;
  const int t0 = (nid & 15) * 128;

  const int cl = clen[b];
  if (t0 >= cl) return;  // block-uniform: whole tile masked, S never read here
  const int ql = qlen[b];

  const int tid = threadIdx.x;
  const int lane = tid & 63;
  const int wv = tid >> 6;
  const int wm = (wv & 1) * 64;
  const int wn = (wv >> 1) * 64;
  const int l15 = lane & 15;
  const int q = lane >> 4;

  // wave-uniform per-mi row-tile activity (j rows >= ql are never read)
  bool mact[4];
#pragma unroll
  for (int i = 0; i < 4; i++) mact[i] = (wm + i * 16) < ql;
  if (!mact[0]) return;  // whole 64-row stripe dead; legal: no barriers below

  // A fragment pointers: [b][ks][str][mi][lane], contiguous per (ks,mi)
  const uint4* ahp = Qhi + (size_t)b * 8192 + (wv & 1) * 256 + lane;
  const uint4* alp = Qlo + (size_t)b * 8192 + (wv & 1) * 256 + lane;
  // B rows: lane (l15,q) owns floats [8q, 8q+8) of row t0+wn+16*ni+l15
  const float* cb = Cm + ((size_t)b * TT + t0 + wn + l15) * DD + q * 8;

  f32x4 acc[4][4] = {};

  for (int ks = 0; ks < 16; ks++) {
    // ---- issue all global loads for this K-step up front (independent)
    float4 cv0[4], cv1[4];
#pragma unroll
    for (int ni = 0; ni < 4; ni++) {
      const float* cp = cb + ni * 16 * DD + ks * BK;
      cv0[ni] = *(const float4*)cp;
      cv1[ni] = *(const float4*)(cp + 4);
    }
    uint4 ahv[4], alv[4];
#pragma unroll
    for (int mi = 0; mi < 4; mi++) {
      if (mact[mi]) {
        ahv[mi] = ahp[ks * 512 + mi * 64];
        alv[mi] = alp[ks * 512 + mi * 64];
      }
    }
    // ---- convert B to split-bf16 in-register
    short8 bh[4], bl[4];
#pragma unroll
    for (int ni = 0; ni < 4; ni++) {
      uint4 h, l;
      pack8(cv0[ni], cv1[ni], h, l);
      bh[ni] = bc8(h);
      bl[ni] = bc8(l);
    }
    // ---- MFMA
#pragma unroll
    for (int mi = 0; mi < 4; mi++) {
      if (!mact[mi]) continue;  // wave-uniform skip: rows never read
      short8 ah = bc8(ahv[mi]);
      short8 al = bc8(alv[mi]);
#pragma unroll
      for (int ni = 0; ni < 4; ni++) {
        acc[mi][ni] = __builtin_amdgcn_mfma_f32_16x16x32_bf16(ah, bh[ni], acc[mi][ni], 0, 0, 0);
        acc[mi][ni] = __builtin_amdgcn_mfma_f32_16x16x32_bf16(al, bh[ni], acc[mi][ni], 0, 0, 0);
        acc[mi][ni] = __builtin_amdgcn_mfma_f32_16x16x32_bf16(ah, bl[ni], acc[mi][ni], 0, 0, 0);
      }
    }
  }

  // epilogue: C/D layout col=lane&15, row=(lane>>4)*4+reg
#pragma unroll
  for (int mi = 0; mi < 4; mi++) {
    if (!mact[mi]) continue;  // rows >= ql: never read by stats/out
#pragma unroll
    for (int ni = 0; ni < 4; ni++) {
      const int j = wm + mi * 16 + q * 4;
      const int t = t0 + wn + ni * 16 + l15;
      float* dst = S + ((size_t)b * JJ + j) * TT + t;
      dst[0 * TT] = acc[mi][ni][0];
      dst[1 * TT] = acc[mi][ni][1];
      dst[2 * TT] = acc[mi][ni][2];
      dst[3 * TT] = acc[mi][ni][3];
    }
  }
}

// ---------------- Kernel B: per-(b,j) softmax stats over valid t -------------
// Single pass: whole valid 2048-row in registers (8 floats/thread), masked
// max+sum. Loads predicated on t<cl: the tail of S is unwritten poison.
__global__ __launch_bounds__(256)
void softmax_stats_kernel(const float* __restrict__ S, const int* __restrict__ qlen,
                          const int* __restrict__ clen, float* __restrict__ m_out,
                          float* __restrict__ r_out) {
  const int j = blockIdx.x;
  const int b = blockIdx.y;
  if (j >= qlen[b]) return;
  const int cl = clen[b];
  const int tid = threadIdx.x;
  const float4* row = (const float4*)(S + ((size_t)b * JJ + j) * TT);

  const float NEG = -3.4e38f;
  float4 v0 = make_float4(NEG, NEG, NEG, NEG);
  float4 v1 = make_float4(NEG, NEG, NEG, NEG);
  const int t0 = tid * 4;
  const int t1 = (tid + 256) * 4;
  if (t0 < cl) v0 = row[tid];          // predicated: skip unwritten tail
  if (t1 < cl) v1 = row[tid + 256];

  float m = NEG;
  m = fmaxf(m, (t0 + 0 < cl) ? v0.x : NEG);
  m = fmaxf(m, (t0 + 1 < cl) ? v0.y : NEG);
  m = fmaxf(m, (t0 + 2 < cl) ? v0.z : NEG);
  m = fmaxf(m, (t0 + 3 < cl) ? v0.w : NEG);
  m = fmaxf(m, (t1 + 0 < cl) ? v1.x : NEG);
  m = fmaxf(m, (t1 + 1 < cl) ? v1.y : NEG);
  m = fmaxf(m, (t1 + 2 < cl) ? v1.z : NEG);
  m = fmaxf(m, (t1 + 3 < cl) ? v1.w : NEG);

  __shared__ float red[8];
#pragma unroll
  for (int off = 32; off > 0; off >>= 1) m = fmaxf(m, __shfl_down(m, off));
  if ((tid & 63) == 0) red[tid >> 6] = m;
  __syncthreads();
  m = fmaxf(fmaxf(red[0], red[1]), fmaxf(red[2], red[3]));

  float s = 0.f;
  s += (t0 + 0 < cl) ? __expf(v0.x - m) : 0.f;
  s += (t0 + 1 < cl) ? __expf(v0.y - m) : 0.f;
  s += (t0 + 2 < cl) ? __expf(v0.z - m) : 0.f;
  s += (t0 + 3 < cl) ? __expf(v0.w - m) : 0.f;
  s += (t1 + 0 < cl) ? __expf(v1.x - m) : 0.f;
  s += (t1 + 1 < cl) ? __expf(v1.y - m) : 0.f;
  s += (t1 + 2 < cl) ? __expf(v1.z - m) : 0.f;
  s += (t1 + 3 < cl) ? __expf(v1.w - m) : 0.f;
#pragma unroll
  for (int off = 32; off > 0; off >>= 1) s += __shfl_down(s, off);
  if ((tid & 63) == 0) red[4 + (tid >> 6)] = s;
  __syncthreads();
  s = red[4] + red[5] + red[6] + red[7];

  if (tid == 0) {
    m_out[(size_t)b * JJ + j] = m;
    r_out[(size_t)b * JJ + j] = 1.f / s;
  }
}

// ---------------- Kernel C: out[b,t] = sum_{j<qlen} exp(S-m)*r ---------------
__global__ __launch_bounds__(256)
void out_kernel(const float* __restrict__ S, const float* __restrict__ m_arr,
                const float* __restrict__ r_arr, const int* __restrict__ qlen,
                const int* __restrict__ clen, float* __restrict__ out) {
  const int b = blockIdx.y;
  const int t = blockIdx.x * 256 + threadIdx.x;
  const int ql = qlen[b];
  const int cl = clen[b];

  __shared__ float lm[JJ];
  __shared__ float lr[JJ];
  if (threadIdx.x < ql) {
    lm[threadIdx.x] = m_arr[(size_t)b * JJ + threadIdx.x];
    lr[threadIdx.x] = r_arr[(size_t)b * JJ + threadIdx.x];
  }
  __syncthreads();

  float acc = 0.f;
  if (t < cl) {
    const float* col = S + (size_t)b * JJ * TT + t;
#pragma unroll 4
    for (int j = 0; j < ql; j++) {
      acc += __expf(col[(size_t)j * TT] - lm[j]) * lr[j];
    }
  }
  out[(size_t)b * TT + t] = acc;
}

extern "C" void kernel_launch(void* const* d_in, const int* in_sizes, int n_in,
                              void* d_out, int out_size, void* d_ws, size_t ws_size,
                              hipStream_t stream) {
  const float* question = (const float*)d_in[0];  // (B,J,D)
  const float* context  = (const float*)d_in[1];  // (B,T,D)
  const int*   qlen     = (const int*)d_in[2];    // (B,)
  const int*   clen     = (const int*)d_in[3];    // (B,)
  const float* weight   = (const float*)d_in[4];  // (D,1)
  float* out = (float*)d_out;                     // (B,T,1) f32

  // Workspace: S (64 MB) + m (B*J) + r (B*J) + Qhi (8 MB) + Qlo (8 MB)
  float* S = (float*)d_ws;
  float* m_arr = S + (size_t)BB * JJ * TT;
  float* r_arr = m_arr + (size_t)BB * JJ;
  uint4* Qhi = (uint4*)(r_arr + (size_t)BB * JJ);
  uint4* Qlo = Qhi + (size_t)BB * 16 * 512;

  qpack_kernel<<<dim3(2048), 256, 0, stream>>>(question, weight, Qhi, Qlo);
  sim_gemm_mfma<<<dim3(1024), 256, 0, stream>>>(Qhi, Qlo, context, qlen, clen, S);
  softmax_stats_kernel<<<dim3(JJ, BB), 256, 0, stream>>>(S, qlen, clen, m_arr, r_arr);
  out_kernel<<<dim3(TT / 256, BB), 256, 0, stream>>>(S, m_arr, r_arr, qlen, clen, out);
}